// Round 1
// baseline (129.079 us; speedup 1.0000x reference)
//
#include <hip/hip_runtime.h>

#define NBLK 12
#define BB 2
#define NPTS 100
#define PP 1024
#define NN 1125
#define NPAD 1152
#define NSCALE 4
#define NG 16
#define KPAD 5
#define CAMTHR 0.2f

#define IC_CHUNKS 9
#define ROWS_PER_CHUNK 125
#define JT_TILES 5

// workspace layout (floats)
#define WS_ROWSUM 0                           // [3][BB][NPAD]  blocks 8..10 (kk=0..2)
#define WS_VS (3 * BB * NPAD)                 // [4][BB][NG][NPAD]
#define WS_PART (WS_VS + 4 * BB * NG * NPAD)  // [IC][BB][NG][NPAD]

// ---------------------------------------------------------------------------
// K1: row sums (+1 for identity) of aug blocks 8..10, all rows.
__global__ void rowsum_kernel(const float* __restrict__ A, float* __restrict__ ws) {
    __shared__ float red[256];
    int rid = blockIdx.x;                 // 3*BB*NN rows
    int i = rid % NN;
    int b = (rid / NN) % BB;
    int kk = rid / (NN * BB);             // 0..2 -> block 8+kk
    int blk = 8 + kk;
    const float* row = A + (((size_t)blk * BB + b) * NN + i) * NN;
    float s = 0.f;
    for (int j = threadIdx.x; j < NN; j += 256) s += row[j];
    red[threadIdx.x] = s;
    __syncthreads();
    for (int st = 128; st > 0; st >>= 1) {
        if (threadIdx.x < st) red[threadIdx.x] += red[threadIdx.x + st];
        __syncthreads();
    }
    if (threadIdx.x == 0) ws[WS_ROWSUM + (kk * BB + b) * NPAD + i] = red[0] + 1.0f;
}

// ---------------------------------------------------------------------------
// K2: initial vectors v1 = row r of normalized aug[11] (stage s=3).
__global__ void initv_kernel(const float* __restrict__ A, const int* __restrict__ pos,
                             float* __restrict__ ws) {
    __shared__ float red[256];
    int g = blockIdx.x % NG;
    int b = blockIdx.x / NG;
    int r = NN - NPTS + pos[b * NG + g];
    const float* row = A + (((size_t)11 * BB + b) * NN + r) * NN;
    float s = 0.f;
    for (int j = threadIdx.x; j < NN; j += 256) s += row[j];
    red[threadIdx.x] = s;
    __syncthreads();
    for (int st = 128; st > 0; st >>= 1) {
        if (threadIdx.x < st) red[threadIdx.x] += red[threadIdx.x + st];
        __syncthreads();
    }
    float inv = 1.0f / (red[0] + 1.0f);
    float* v = ws + WS_VS + ((3 * BB + b) * NG + g) * NPAD;
    for (int j = threadIdx.x; j < NN; j += 256)
        v[j] = (row[j] + (j == r ? 1.0f : 0.0f)) * inv;
}

// ---------------------------------------------------------------------------
// K3a: partial of V_next[g][j] = sum_i (V[g][i]/rs[i]) * A[i][j] over an i-chunk.
__global__ void stage_partial_kernel(const float* __restrict__ A, float* __restrict__ ws,
                                     int blk, int kk, int s_in) {
    __shared__ float Wl[NG * ROWS_PER_CHUNK];
    int x = blockIdx.x;
    int jt = x % JT_TILES;
    int b = (x / JT_TILES) % BB;
    int ic = x / (JT_TILES * BB);
    int i0 = ic * ROWS_PER_CHUNK;
    const float* rs = ws + WS_ROWSUM + (kk * BB + b) * NPAD;
    const float* vin = ws + WS_VS + ((s_in * BB + b) * NG) * NPAD;
    for (int idx = threadIdx.x; idx < NG * ROWS_PER_CHUNK; idx += 256) {
        int g = idx / ROWS_PER_CHUNK;
        int il = idx % ROWS_PER_CHUNK;
        Wl[idx] = vin[g * NPAD + i0 + il] / rs[i0 + il];
    }
    __syncthreads();
    int j = jt * 256 + threadIdx.x;
    if (j < NN) {
        float acc[NG];
#pragma unroll
        for (int g = 0; g < NG; ++g) acc[g] = 0.f;
        const float* Ab = A + (((size_t)blk * BB + b) * NN + i0) * NN + j;
        for (int il = 0; il < ROWS_PER_CHUNK; ++il) {
            float a = Ab[(size_t)il * NN];
#pragma unroll
            for (int g = 0; g < NG; ++g) acc[g] += Wl[g * ROWS_PER_CHUNK + il] * a;
        }
        float* po = ws + WS_PART + ((ic * BB + b) * NG) * NPAD + j;
#pragma unroll
        for (int g = 0; g < NG; ++g) po[(size_t)g * NPAD] = acc[g];
    }
}

// ---------------------------------------------------------------------------
// K3b: reduce partials + identity term w[j] -> V stage s_out.
__global__ void stage_reduce_kernel(float* __restrict__ ws, int kk, int s_in, int s_out) {
    int t = blockIdx.x * 256 + threadIdx.x;   // covers BB*NG*NPAD
    int j = t % NPAD;
    int g = (t / NPAD) % NG;
    int b = t / (NPAD * NG);
    if (b >= BB || j >= NN) return;
    float w = ws[WS_VS + ((s_in * BB + b) * NG + g) * NPAD + j]
            / ws[WS_ROWSUM + (kk * BB + b) * NPAD + j];
    float s = w;
    for (int ic = 0; ic < IC_CHUNKS; ++ic)
        s += ws[WS_PART + ((ic * BB + b) * NG + g) * NPAD + j];
    ws[WS_VS + ((s_out * BB + b) * NG + g) * NPAD + j] = s;
}

// ---------------------------------------------------------------------------
// K4: per-image normalize, binarize, morph close (zero-pad), bbox.
__global__ void post_kernel(const float* __restrict__ ws, float* __restrict__ out) {
    __shared__ float redA[1024];
    __shared__ float redB[1024];
    __shared__ float img[1024];
    __shared__ float tmp[1024];
    int idx = blockIdx.x;                 // (b*NG+g)*NSCALE + s
    int s = idx % NSCALE;
    int g = (idx / NSCALE) % NG;
    int b = idx / (NSCALE * NG);
    int p = threadIdx.x;                  // 0..1023
    float cam = ws[WS_VS + ((s * BB + b) * NG + g) * NPAD + 1 + p];
    redA[p] = cam;
    redB[p] = cam;
    __syncthreads();
    for (int st = 512; st > 0; st >>= 1) {
        if (p < st) {
            redA[p] = fminf(redA[p], redA[p + st]);
            redB[p] = fmaxf(redB[p], redB[p + st]);
        }
        __syncthreads();
    }
    float mn = redA[0], mx = redB[0];
    float camn = (cam - mn) / (mx - mn + 1e-6f);
    out[(size_t)idx * PP + p] = camn;
    float bin = camn >= CAMTHR ? 1.0f : 0.0f;
    __syncthreads();                      // done reading redA/redB
    img[p] = bin;
    __syncthreads();
    int y = p >> 5, x = p & 31;
    // dilate horizontal (pad-0 under max == clip)
    float m = 0.f;
    for (int dx = -KPAD; dx <= KPAD; ++dx) {
        int xx = x + dx;
        if (xx >= 0 && xx < 32) m = fmaxf(m, img[(y << 5) | xx]);
    }
    tmp[p] = m;
    __syncthreads();
    // dilate vertical
    m = 0.f;
    for (int dy = -KPAD; dy <= KPAD; ++dy) {
        int yy = y + dy;
        if (yy >= 0 && yy < 32) m = fmaxf(m, tmp[(yy << 5) | x]);
    }
    __syncthreads();
    img[p] = m;                           // dilated
    __syncthreads();
    // erode horizontal, zero-pad: border forced 0
    float e;
    if (x < KPAD || x > 31 - KPAD) {
        e = 0.f;
    } else {
        e = 1e30f;
        for (int dx = -KPAD; dx <= KPAD; ++dx) e = fminf(e, img[(y << 5) | (x + dx)]);
    }
    tmp[p] = e;
    __syncthreads();
    float ev;
    if (y < KPAD || y > 31 - KPAD) {
        ev = 0.f;
    } else {
        ev = 1e30f;
        for (int dy = -KPAD; dy <= KPAD; ++dy) ev = fminf(ev, tmp[((y + dy) << 5) | x]);
    }
    out[(size_t)(BB * NG * NSCALE) * PP + (size_t)idx * PP + p] = ev;
    bool fg = ev > 0.5f;
    // bbox via min/max reductions over all pixels
    redA[p] = fg ? (float)x : 1e9f;
    redB[p] = fg ? (float)x : -1e9f;
    __syncthreads();
    for (int st = 512; st > 0; st >>= 1) {
        if (p < st) {
            redA[p] = fminf(redA[p], redA[p + st]);
            redB[p] = fmaxf(redB[p], redB[p + st]);
        }
        __syncthreads();
    }
    float xmin = redA[0], xmax = redB[0];
    __syncthreads();
    redA[p] = fg ? (float)y : 1e9f;
    redB[p] = fg ? (float)y : -1e9f;
    __syncthreads();
    for (int st = 512; st > 0; st >>= 1) {
        if (p < st) {
            redA[p] = fminf(redA[p], redA[p + st]);
            redB[p] = fmaxf(redB[p], redB[p + st]);
        }
        __syncthreads();
    }
    if (p == 0) {
        float ymin = redA[0], ymax = redB[0];
        float* bb = out + (size_t)(BB * NG * NSCALE) * PP * 2 + (size_t)idx * 4;
        if (xmax < -1e8f) {
            bb[0] = 0.f; bb[1] = 0.f; bb[2] = 1.f; bb[3] = 1.f;
        } else {
            bb[0] = xmin; bb[1] = ymin; bb[2] = xmax; bb[3] = ymax;
        }
    }
}

extern "C" void kernel_launch(void* const* d_in, const int* in_sizes, int n_in,
                              void* d_out, int out_size, void* d_ws, size_t ws_size,
                              hipStream_t stream) {
    const float* A = (const float*)d_in[0];
    const int* pos = (const int*)d_in[1];
    float* out = (float*)d_out;
    float* ws = (float*)d_ws;

    rowsum_kernel<<<3 * BB * NN, 256, 0, stream>>>(A, ws);
    initv_kernel<<<BB * NG, 256, 0, stream>>>(A, pos, ws);
    for (int t = 1; t <= 3; ++t) {
        int blk = 11 - t;        // 10, 9, 8
        int kk = blk - 8;        // 2, 1, 0
        int s_in = 4 - t;        // 3, 2, 1
        int s_out = 3 - t;       // 2, 1, 0
        stage_partial_kernel<<<IC_CHUNKS * BB * JT_TILES, 256, 0, stream>>>(A, ws, blk, kk, s_in);
        stage_reduce_kernel<<<(BB * NG * NPAD) / 256, 256, 0, stream>>>(ws, kk, s_in, s_out);
    }
    post_kernel<<<BB * NG * NSCALE, 1024, 0, stream>>>(ws, out);
}

// Round 2
// 49.977 us; speedup vs baseline: 2.5828x; 2.5828x over previous
//
#include <hip/hip_runtime.h>

#define NBLK 12
#define BB 2
#define NPTS 100
#define PP 1024
#define NN 1125
#define NPAD 1152
#define NSCALE 4
#define NG 16
#define KPAD 5
#define CAMTHR 0.2f

#define IC_CHUNKS 25
#define ROWS_PER_CHUNK 45
#define JT_TILES 5

#define N_ROWSUM (3 * BB * NN)            // 6750 rowsum tasks
#define N_INITV (BB * NG)                 // 32 initv tasks

// workspace layout (floats)
#define WS_ROWSUM 0                           // [3][BB][NPAD]  blocks 8..10 (kk=0..2)
#define WS_VS (3 * BB * NPAD)                 // [4][BB][NG][NPAD]
#define WS_PART (WS_VS + 4 * BB * NG * NPAD)  // [IC][BB][NG][NPAD]

__device__ __forceinline__ float wave_sum(float s) {
#pragma unroll
    for (int m = 32; m > 0; m >>= 1) s += __shfl_xor(s, m, 64);
    return s;
}

// ---------------------------------------------------------------------------
// K1: wave-per-row. Tasks 0..6749: rowsums (+1) of aug blocks 8..10.
//     Tasks 6750..6781: initial vectors v3 = row r of normalized aug[11].
__global__ void prep_kernel(const float* __restrict__ A, const int* __restrict__ pos,
                            float* __restrict__ ws) {
    int wave = threadIdx.x >> 6;
    int lane = threadIdx.x & 63;
    int task = blockIdx.x * 4 + wave;
    if (task < N_ROWSUM) {
        int i = task % NN;
        int b = (task / NN) % BB;
        int kk = task / (NN * BB);
        const float* row = A + (((size_t)(8 + kk) * BB + b) * NN + i) * NN;
        float s = 0.f;
#pragma unroll
        for (int k = 0; k < 17; ++k) s += row[lane + 64 * k];
        if (lane < NN - 17 * 64) s += row[lane + 17 * 64];
        s = wave_sum(s);
        if (lane == 0) ws[WS_ROWSUM + (kk * BB + b) * NPAD + i] = s + 1.0f;
    } else if (task < N_ROWSUM + N_INITV) {
        int t = task - N_ROWSUM;
        int g = t % NG;
        int b = t / NG;
        int r = NN - NPTS + pos[b * NG + g];
        const float* row = A + (((size_t)11 * BB + b) * NN + r) * NN;
        float s = 0.f;
#pragma unroll
        for (int k = 0; k < 17; ++k) s += row[lane + 64 * k];
        if (lane < NN - 17 * 64) s += row[lane + 17 * 64];
        s = wave_sum(s);
        float inv = 1.0f / (s + 1.0f);
        float* v = ws + WS_VS + ((3 * BB + b) * NG + g) * NPAD;
        for (int j = lane; j < NN; j += 64)
            v[j] = (row[j] + (j == r ? 1.0f : 0.0f)) * inv;
    }
}

// ---------------------------------------------------------------------------
// K2: partial of V_next[g][j] = sum_i (V[g][i]/rs[i]) * A[i][j] over an i-chunk.
__global__ void stage_partial_kernel(const float* __restrict__ A, float* __restrict__ ws,
                                     int blk, int kk, int s_in) {
    __shared__ float Wl[ROWS_PER_CHUNK * NG];   // [il][g] -- contiguous g for b128 broadcast
    int x = blockIdx.x;
    int jt = x % JT_TILES;
    int b = (x / JT_TILES) % BB;
    int ic = x / (JT_TILES * BB);
    int i0 = ic * ROWS_PER_CHUNK;
    const float* rs = ws + WS_ROWSUM + (kk * BB + b) * NPAD;
    const float* vin = ws + WS_VS + ((s_in * BB + b) * NG) * NPAD;
    for (int idx = threadIdx.x; idx < ROWS_PER_CHUNK * NG; idx += 256) {
        int il = idx / NG;
        int g = idx % NG;
        Wl[idx] = vin[g * NPAD + i0 + il] / rs[i0 + il];
    }
    __syncthreads();
    int j = jt * 256 + threadIdx.x;
    if (j < NN) {
        float acc[NG];
#pragma unroll
        for (int g = 0; g < NG; ++g) acc[g] = 0.f;
        const float* Ab = A + (((size_t)blk * BB + b) * NN + i0) * NN + j;
#pragma unroll 5
        for (int il = 0; il < ROWS_PER_CHUNK; ++il) {
            float a = Ab[(size_t)il * NN];
            const float* wrow = &Wl[il * NG];
#pragma unroll
            for (int g = 0; g < NG; ++g) acc[g] += wrow[g] * a;
        }
        float* po = ws + WS_PART + ((ic * BB + b) * NG) * NPAD + j;
#pragma unroll
        for (int g = 0; g < NG; ++g) po[(size_t)g * NPAD] = acc[g];
    }
}

// ---------------------------------------------------------------------------
// K3: reduce partials + identity term w[j]/rs[j] -> V stage s_out.
__global__ void stage_reduce_kernel(float* __restrict__ ws, int kk, int s_in, int s_out) {
    int t = blockIdx.x * 256 + threadIdx.x;   // covers BB*NG*NPAD
    int j = t % NPAD;
    int g = (t / NPAD) % NG;
    int b = t / (NPAD * NG);
    if (b >= BB || j >= NN) return;
    float s = ws[WS_VS + ((s_in * BB + b) * NG + g) * NPAD + j]
            / ws[WS_ROWSUM + (kk * BB + b) * NPAD + j];
#pragma unroll
    for (int ic = 0; ic < IC_CHUNKS; ++ic)
        s += ws[WS_PART + ((ic * BB + b) * NG + g) * NPAD + j];
    ws[WS_VS + ((s_out * BB + b) * NG + g) * NPAD + j] = s;
}

// ---------------------------------------------------------------------------
// K4: per-image normalize, binarize, morph close (zero-pad), bbox.
__global__ void post_kernel(const float* __restrict__ ws, float* __restrict__ out) {
    __shared__ float redA[1024];
    __shared__ float redB[1024];
    __shared__ float img[1024];
    __shared__ float tmp[1024];
    int idx = blockIdx.x;                 // (b*NG+g)*NSCALE + s
    int s = idx % NSCALE;
    int g = (idx / NSCALE) % NG;
    int b = idx / (NSCALE * NG);
    int p = threadIdx.x;                  // 0..1023
    float cam = ws[WS_VS + ((s * BB + b) * NG + g) * NPAD + 1 + p];
    redA[p] = cam;
    redB[p] = cam;
    __syncthreads();
    for (int st = 512; st > 0; st >>= 1) {
        if (p < st) {
            redA[p] = fminf(redA[p], redA[p + st]);
            redB[p] = fmaxf(redB[p], redB[p + st]);
        }
        __syncthreads();
    }
    float mn = redA[0], mx = redB[0];
    float camn = (cam - mn) / (mx - mn + 1e-6f);
    out[(size_t)idx * PP + p] = camn;
    float bin = camn >= CAMTHR ? 1.0f : 0.0f;
    __syncthreads();                      // done reading redA/redB
    img[p] = bin;
    __syncthreads();
    int y = p >> 5, x = p & 31;
    // dilate horizontal (pad-0 under max == clip)
    float m = 0.f;
    for (int dx = -KPAD; dx <= KPAD; ++dx) {
        int xx = x + dx;
        if (xx >= 0 && xx < 32) m = fmaxf(m, img[(y << 5) | xx]);
    }
    tmp[p] = m;
    __syncthreads();
    // dilate vertical
    m = 0.f;
    for (int dy = -KPAD; dy <= KPAD; ++dy) {
        int yy = y + dy;
        if (yy >= 0 && yy < 32) m = fmaxf(m, tmp[(yy << 5) | x]);
    }
    __syncthreads();
    img[p] = m;                           // dilated
    __syncthreads();
    // erode horizontal, zero-pad: border forced 0
    float e;
    if (x < KPAD || x > 31 - KPAD) {
        e = 0.f;
    } else {
        e = 1e30f;
        for (int dx = -KPAD; dx <= KPAD; ++dx) e = fminf(e, img[(y << 5) | (x + dx)]);
    }
    tmp[p] = e;
    __syncthreads();
    float ev;
    if (y < KPAD || y > 31 - KPAD) {
        ev = 0.f;
    } else {
        ev = 1e30f;
        for (int dy = -KPAD; dy <= KPAD; ++dy) ev = fminf(ev, tmp[((y + dy) << 5) | x]);
    }
    out[(size_t)(BB * NG * NSCALE) * PP + (size_t)idx * PP + p] = ev;
    bool fg = ev > 0.5f;
    // bbox via min/max reductions over all pixels
    redA[p] = fg ? (float)x : 1e9f;
    redB[p] = fg ? (float)x : -1e9f;
    __syncthreads();
    for (int st = 512; st > 0; st >>= 1) {
        if (p < st) {
            redA[p] = fminf(redA[p], redA[p + st]);
            redB[p] = fmaxf(redB[p], redB[p + st]);
        }
        __syncthreads();
    }
    float xmin = redA[0], xmax = redB[0];
    __syncthreads();
    redA[p] = fg ? (float)y : 1e9f;
    redB[p] = fg ? (float)y : -1e9f;
    __syncthreads();
    for (int st = 512; st > 0; st >>= 1) {
        if (p < st) {
            redA[p] = fminf(redA[p], redA[p + st]);
            redB[p] = fmaxf(redB[p], redB[p + st]);
        }
        __syncthreads();
    }
    if (p == 0) {
        float ymin = redA[0], ymax = redB[0];
        float* bb = out + (size_t)(BB * NG * NSCALE) * PP * 2 + (size_t)idx * 4;
        if (xmax < -1e8f) {
            bb[0] = 0.f; bb[1] = 0.f; bb[2] = 1.f; bb[3] = 1.f;
        } else {
            bb[0] = xmin; bb[1] = ymin; bb[2] = xmax; bb[3] = ymax;
        }
    }
}

extern "C" void kernel_launch(void* const* d_in, const int* in_sizes, int n_in,
                              void* d_out, int out_size, void* d_ws, size_t ws_size,
                              hipStream_t stream) {
    const float* A = (const float*)d_in[0];
    const int* pos = (const int*)d_in[1];
    float* out = (float*)d_out;
    float* ws = (float*)d_ws;

    int prep_blocks = (N_ROWSUM + N_INITV + 3) / 4;
    prep_kernel<<<prep_blocks, 256, 0, stream>>>(A, pos, ws);
    for (int t = 1; t <= 3; ++t) {
        int blk = 11 - t;        // 10, 9, 8
        int kk = blk - 8;        // 2, 1, 0
        int s_in = 4 - t;        // 3, 2, 1
        int s_out = 3 - t;       // 2, 1, 0
        stage_partial_kernel<<<IC_CHUNKS * BB * JT_TILES, 256, 0, stream>>>(A, ws, blk, kk, s_in);
        stage_reduce_kernel<<<(BB * NG * NPAD + 255) / 256, 256, 0, stream>>>(ws, kk, s_in, s_out);
    }
    post_kernel<<<BB * NG * NSCALE, 1024, 0, stream>>>(ws, out);
}